// Round 9
// baseline (203.105 us; speedup 1.0000x reference)
//
#include <hip/hip_runtime.h>

#define TW 64        // tile width  (lap pixels)
#define TH 32        // tile height
#define DR 18        // down rows incl. 1-ring halo (TH/2 + 2)
#define SDP 35       // s_down row stride (odd -> bank spread)
#define NTASK (DR * 17)   // 306 down-pair tasks per tile

__device__ __forceinline__ int refl(int t, int n) {
    if (t < 0) t = -t;
    if (t >= n) t = 2 * (n - 1) - t;
    return t;
}

// One fused pyramid level: down = gauss5(cur)[::2,::2]; lap = cur - up(down).
// Single-barrier structure: per thread, prefetch lap's cur pixels (2 float4),
// then compute a pair of down values straight from global (10 independent
// float4 loads, separable filter in registers) -> s_down (2.5KB LDS) ->
// barrier -> up-stencil + subtract from prefetched cur. Plain stores (NT
// stores measured 1.7x write amplification + 2.3x slowdown in R8).
__global__ __launch_bounds__(256, 8) void lap_level_kernel(
    const float* __restrict__ cur, float* __restrict__ lap,
    float* __restrict__ down, int H, int W)
{
    __shared__ float s_down[DR][SDP];

    const int x0 = blockIdx.x * TW, y0 = blockIdx.y * TH;
    const int img = blockIdx.z;
    const int Hh = H >> 1, Wh = W >> 1;
    const int tid = threadIdx.x;
    const int tx = tid & 15, ty = tid >> 4;

    const float* curb = cur + (size_t)img * H * W;

    // ---- P: prefetch this thread's lap cur pixels (always in-image) ----
    const int i0 = y0 + 2 * ty, j0 = x0 + 4 * tx;
    const float* cvp = curb + (size_t)i0 * W + j0;
    const float4 cve = *(const float4*)(cvp);
    const float4 cvo = *(const float4*)(cvp + (size_t)W);

    // ---- B: down pairs directly from global ----
    float* downb = down + (size_t)img * Hh * Wh;
    const bool border = (x0 == 0) | (y0 == 0) | (x0 + TW == W) | (y0 + TH == H);
    if (!border) {
        for (int k = tid; k < NTASK; k += 256) {
            unsigned a = (unsigned)k / 17u;
            unsigned b2 = (unsigned)k - a * 17u;
            const float* p = curb + (size_t)(y0 - 4 + 2 * (int)a) * W + (x0 - 4 + 4 * (int)b2);
            float4 A0 = *(const float4*)(p);
            float4 B0 = *(const float4*)(p + 4);
            float4 A1 = *(const float4*)(p + (size_t)W);
            float4 B1 = *(const float4*)(p + (size_t)W + 4);
            float4 A2 = *(const float4*)(p + (size_t)2 * W);
            float4 B2 = *(const float4*)(p + (size_t)2 * W + 4);
            float4 A3 = *(const float4*)(p + (size_t)3 * W);
            float4 B3 = *(const float4*)(p + (size_t)3 * W + 4);
            float4 A4 = *(const float4*)(p + (size_t)4 * W);
            float4 B4 = *(const float4*)(p + (size_t)4 * W + 4);
            float s0 = A0.x + 4.f * A1.x + 6.f * A2.x + 4.f * A3.x + A4.x;
            float s1 = A0.y + 4.f * A1.y + 6.f * A2.y + 4.f * A3.y + A4.y;
            float s2 = A0.z + 4.f * A1.z + 6.f * A2.z + 4.f * A3.z + A4.z;
            float s3 = A0.w + 4.f * A1.w + 6.f * A2.w + 4.f * A3.w + A4.w;
            float s4 = B0.x + 4.f * B1.x + 6.f * B2.x + 4.f * B3.x + B4.x;
            float s5 = B0.y + 4.f * B1.y + 6.f * B2.y + 4.f * B3.y + B4.y;
            float s6 = B0.z + 4.f * B1.z + 6.f * B2.z + 4.f * B3.z + B4.z;
            float v0 = (s0 + 4.f * s1 + 6.f * s2 + 4.f * s3 + s4) * (1.f / 256.f);
            float v1 = (s2 + 4.f * s3 + 6.f * s4 + 4.f * s5 + s6) * (1.f / 256.f);
            s_down[a][2 * b2] = v0;
            s_down[a][2 * b2 + 1] = v1;
            if (a - 1u < 16u) {
                size_t rowoff = (size_t)((y0 >> 1) - 1 + (int)a) * Wh + ((x0 >> 1) - 1);
                if (b2 >= 1u) downb[rowoff + 2 * b2] = v0;
                if (b2 <= 15u) downb[rowoff + 2 * b2 + 1] = v1;
            }
        }
    } else {
        for (int k = tid; k < NTASK; k += 256) {
            unsigned a = (unsigned)k / 17u;
            unsigned b2 = (unsigned)k - a * 17u;
            const float wv[5] = {1.f, 4.f, 6.f, 4.f, 1.f};
            float s[7];
#pragma unroll
            for (int c = 0; c < 7; ++c) {
                int gx = refl(x0 - 4 + 4 * (int)b2 + c, W);
                float acc = 0.f;
#pragma unroll
                for (int u = 0; u < 5; ++u)
                    acc += wv[u] * curb[(size_t)refl(y0 - 4 + 2 * (int)a + u, H) * W + gx];
                s[c] = acc;
            }
            float v0 = (s[0] + 4.f * s[1] + 6.f * s[2] + 4.f * s[3] + s[4]) * (1.f / 256.f);
            float v1 = (s[2] + 4.f * s[3] + 6.f * s[4] + 4.f * s[5] + s[6]) * (1.f / 256.f);
            s_down[a][2 * b2] = v0;
            s_down[a][2 * b2 + 1] = v1;
            if (a - 1u < 16u) {
                size_t rowoff = (size_t)((y0 >> 1) - 1 + (int)a) * Wh + ((x0 >> 1) - 1);
                if (b2 >= 1u) downb[rowoff + 2 * b2] = v0;
                if (b2 <= 15u) downb[rowoff + 2 * b2 + 1] = v1;
            }
        }
    }
    __syncthreads();

    // ---- C: lap = cur - up(down); thread = 4 wide x 2 tall; parity static ----
    float d0[4], d1[4], d2[4];
#pragma unroll
    for (int c = 0; c < 4; ++c) {
        d0[c] = s_down[ty + 0][2 * tx + c];
        d1[c] = s_down[ty + 1][2 * tx + c];
        d2[c] = s_down[ty + 2][2 * tx + c];
    }
    float ce[4], co[4];
#pragma unroll
    for (int c = 0; c < 4; ++c) {
        ce[c] = d0[c] + 6.f * d1[c] + d2[c];
        co[c] = 4.f * (d1[c] + d2[c]);
    }
    float* lapb = lap + (size_t)img * H * W;
    float4 oe, oo;
    oe.x = cve.x - (ce[0] + 6.f * ce[1] + ce[2]) * (1.f / 64.f);
    oe.y = cve.y - 4.f * (ce[1] + ce[2]) * (1.f / 64.f);
    oe.z = cve.z - (ce[1] + 6.f * ce[2] + ce[3]) * (1.f / 64.f);
    oe.w = cve.w - 4.f * (ce[2] + ce[3]) * (1.f / 64.f);
    oo.x = cvo.x - (co[0] + 6.f * co[1] + co[2]) * (1.f / 64.f);
    oo.y = cvo.y - 4.f * (co[1] + co[2]) * (1.f / 64.f);
    oo.z = cvo.z - (co[1] + 6.f * co[2] + co[3]) * (1.f / 64.f);
    oo.w = cvo.w - 4.f * (co[2] + co[3]) * (1.f / 64.f);
    *(float4*)(lapb + (size_t)i0 * W + j0) = oe;
    *(float4*)(lapb + (size_t)(i0 + 1) * W + j0) = oo;
}

extern "C" void kernel_launch(void* const* d_in, const int* in_sizes, int n_in,
                              void* d_out, int out_size, void* d_ws, size_t ws_size,
                              hipStream_t stream) {
    const float* img = (const float*)d_in[0];
    float* out = (float*)d_out;

    const long long BC = 8LL * 3;
    const long long n0 = BC * 1024 * 1024;
    const long long n1 = BC * 512 * 512;
    const long long n2 = BC * 256 * 256;

    float* out0 = out;            // lap0
    float* out1 = out0 + n0;      // lap1
    float* out2 = out1 + n1;      // lap2
    float* out3 = out2 + n2;      // down2

    float* ws0 = (float*)d_ws;    // down0
    float* ws1 = ws0 + n1;        // down1

    lap_level_kernel<<<dim3(1024 / TW, 1024 / TH, (int)BC), 256, 0, stream>>>(
        img, out0, ws0, 1024, 1024);
    lap_level_kernel<<<dim3(512 / TW, 512 / TH, (int)BC), 256, 0, stream>>>(
        ws0, out1, ws1, 512, 512);
    lap_level_kernel<<<dim3(256 / TW, 256 / TH, (int)BC), 256, 0, stream>>>(
        ws1, out2, out3, 256, 256);
}

// Round 10
// 111.492 us; speedup vs baseline: 1.8217x; 1.8217x over previous
//
#include <hip/hip_runtime.h>

#define TW 128       // tile width  (lap pixels)
#define TH 32        // tile height
#define DR 18        // tmp/down rows incl. 1-ring halo (TH/2 + 2)
#define NC4 34       // float4 col-chunks per tmp row (136 cols = TW + 8)
#define TMPP 140     // s_tmp row stride (floats, 16B-multiple)
#define SDP 67       // s_down row stride (odd -> bank spread)

__device__ __forceinline__ int refl(int t, int n) {
    if (t < 0) t = -t;
    if (t >= n) t = 2 * (n - 1) - t;
    return t;
}

// One fused pyramid level: down = gauss5(cur)[::2,::2]; lap = cur - up(down).
// R6 3-phase shape (best measured) + double-row vertical pass (7 global rows
// feed 2 tmp rows; 30% fewer reads, 7 loads in flight) + 128x32 tile.
// No values held across phases (R8/R9 spill lesson: prefetch across a heavy
// phase inflated WRITE_SIZE by ~90MB of scratch traffic). Halo down values
// follow the chain convention (reflect inherited from reflected reads +
// kernel symmetry), exactly what the up-stencil needs (validated R3-R6).
__global__ __launch_bounds__(256, 8) void lap_level_kernel(
    const float* __restrict__ cur, float* __restrict__ lap,
    float* __restrict__ down, int H, int W)
{
    __shared__ float s_tmp[DR][TMPP];   // vertical 5-tap at even rows
    __shared__ float s_down[DR][SDP];   // down tile + halo ring

    const int x0 = blockIdx.x * TW, y0 = blockIdx.y * TH;
    const int img = blockIdx.z;
    const int Hh = H >> 1, Wh = W >> 1;
    const int tid = threadIdx.x;

    const float* curb = cur + (size_t)img * H * W;

    // ---- Bv: 9 double-row tasks x 34 chunks. Task (e,c4): input rows
    // y0-4+4e+u (u=0..6) at cols colg..colg+3 -> tmp rows 2e (u=0..4) and
    // 2e+1 (u=2..6). Row reflect always (cheap); col reflect only on the
    // two edge chunks of x-border blocks. ----
    for (int k = tid; k < 9 * NC4; k += 256) {
        int e = k / NC4, c4 = k - e * NC4;
        int colg = x0 - 4 + 4 * c4;
        int rows[7];
#pragma unroll
        for (int u = 0; u < 7; ++u) rows[u] = refl(y0 - 4 + 4 * e + u, H);
        float4 r[7];
        if (colg >= 0 && colg + 3 < W) {
#pragma unroll
            for (int u = 0; u < 7; ++u)
                r[u] = *(const float4*)(curb + (size_t)rows[u] * W + colg);
        } else {
            int gx[4];
#pragma unroll
            for (int cc = 0; cc < 4; ++cc) gx[cc] = refl(colg + cc, W);
#pragma unroll
            for (int u = 0; u < 7; ++u) {
                const float* rp = curb + (size_t)rows[u] * W;
                r[u].x = rp[gx[0]]; r[u].y = rp[gx[1]];
                r[u].z = rp[gx[2]]; r[u].w = rp[gx[3]];
            }
        }
        float4 t0, t1;
        t0.x = r[0].x + 4.f * r[1].x + 6.f * r[2].x + 4.f * r[3].x + r[4].x;
        t0.y = r[0].y + 4.f * r[1].y + 6.f * r[2].y + 4.f * r[3].y + r[4].y;
        t0.z = r[0].z + 4.f * r[1].z + 6.f * r[2].z + 4.f * r[3].z + r[4].z;
        t0.w = r[0].w + 4.f * r[1].w + 6.f * r[2].w + 4.f * r[3].w + r[4].w;
        t1.x = r[2].x + 4.f * r[3].x + 6.f * r[4].x + 4.f * r[5].x + r[6].x;
        t1.y = r[2].y + 4.f * r[3].y + 6.f * r[4].y + 4.f * r[5].y + r[6].y;
        t1.z = r[2].z + 4.f * r[3].z + 6.f * r[4].z + 4.f * r[5].z + r[6].z;
        t1.w = r[2].w + 4.f * r[3].w + 6.f * r[4].w + 4.f * r[5].w + r[6].w;
        *(float4*)&s_tmp[2 * e][4 * c4] = t0;
        *(float4*)&s_tmp[2 * e + 1][4 * c4] = t1;
    }
    __syncthreads();

    // ---- Bh: horizontal 5-tap; 2 down values per task from 2 aligned f4 ----
    float* downb = down + (size_t)img * Hh * Wh;
    for (int k = tid; k < DR * 33; k += 256) {
        int a = k / 33, b2 = k - a * 33;
        float4 A = *(const float4*)&s_tmp[a][4 * b2];
        float4 B = *(const float4*)&s_tmp[a][4 * b2 + 4];
        float v0 = (A.x + 4.f * A.y + 6.f * A.z + 4.f * A.w + B.x) * (1.f / 256.f);
        float v1 = (A.z + 4.f * A.w + 6.f * B.x + 4.f * B.y + B.z) * (1.f / 256.f);
        s_down[a][2 * b2] = v0;
        s_down[a][2 * b2 + 1] = v1;
        if ((unsigned)(a - 1) < 16u) {   // interior down rows
            size_t rowoff = (size_t)((y0 >> 1) - 1 + a) * Wh + ((x0 >> 1) - 1);
            if (b2 >= 1) downb[rowoff + 2 * b2] = v0;        // c in [1,64]
            if (b2 <= 31) downb[rowoff + 2 * b2 + 1] = v1;
        }
    }
    __syncthreads();

    // ---- C: lap = cur - up(down); thread = 8 wide x 2 tall; parity static ----
    const int tx = tid & 15, ty = tid >> 4;
    float d0[6], d1[6], d2[6];
#pragma unroll
    for (int c = 0; c < 6; ++c) {
        d0[c] = s_down[ty + 0][4 * tx + c];
        d1[c] = s_down[ty + 1][4 * tx + c];
        d2[c] = s_down[ty + 2][4 * tx + c];
    }
    float ce[6], co[6];
#pragma unroll
    for (int c = 0; c < 6; ++c) {
        ce[c] = d0[c] + 6.f * d1[c] + d2[c];
        co[c] = 4.f * (d1[c] + d2[c]);
    }
    const int i0 = y0 + 2 * ty, j0 = x0 + 8 * tx;
    const float* cvp = curb + (size_t)i0 * W + j0;
    float4 ce0 = *(const float4*)(cvp);
    float4 ce1 = *(const float4*)(cvp + 4);
    float4 co0 = *(const float4*)(cvp + (size_t)W);
    float4 co1 = *(const float4*)(cvp + (size_t)W + 4);
    float4 oe0, oe1, oo0, oo1;
    oe0.x = ce0.x - (ce[0] + 6.f * ce[1] + ce[2]) * (1.f / 64.f);
    oe0.y = ce0.y - 4.f * (ce[1] + ce[2]) * (1.f / 64.f);
    oe0.z = ce0.z - (ce[1] + 6.f * ce[2] + ce[3]) * (1.f / 64.f);
    oe0.w = ce0.w - 4.f * (ce[2] + ce[3]) * (1.f / 64.f);
    oe1.x = ce1.x - (ce[2] + 6.f * ce[3] + ce[4]) * (1.f / 64.f);
    oe1.y = ce1.y - 4.f * (ce[3] + ce[4]) * (1.f / 64.f);
    oe1.z = ce1.z - (ce[3] + 6.f * ce[4] + ce[5]) * (1.f / 64.f);
    oe1.w = ce1.w - 4.f * (ce[4] + ce[5]) * (1.f / 64.f);
    oo0.x = co0.x - (co[0] + 6.f * co[1] + co[2]) * (1.f / 64.f);
    oo0.y = co0.y - 4.f * (co[1] + co[2]) * (1.f / 64.f);
    oo0.z = co0.z - (co[1] + 6.f * co[2] + co[3]) * (1.f / 64.f);
    oo0.w = co0.w - 4.f * (co[2] + co[3]) * (1.f / 64.f);
    oo1.x = co1.x - (co[2] + 6.f * co[3] + co[4]) * (1.f / 64.f);
    oo1.y = co1.y - 4.f * (co[3] + co[4]) * (1.f / 64.f);
    oo1.z = co1.z - (co[3] + 6.f * co[4] + co[5]) * (1.f / 64.f);
    oo1.w = co1.w - 4.f * (co[4] + co[5]) * (1.f / 64.f);

    float* lapb = lap + (size_t)img * H * W;
    *(float4*)(lapb + (size_t)i0 * W + j0) = oe0;
    *(float4*)(lapb + (size_t)i0 * W + j0 + 4) = oe1;
    *(float4*)(lapb + (size_t)(i0 + 1) * W + j0) = oo0;
    *(float4*)(lapb + (size_t)(i0 + 1) * W + j0 + 4) = oo1;
}

extern "C" void kernel_launch(void* const* d_in, const int* in_sizes, int n_in,
                              void* d_out, int out_size, void* d_ws, size_t ws_size,
                              hipStream_t stream) {
    const float* img = (const float*)d_in[0];
    float* out = (float*)d_out;

    const long long BC = 8LL * 3;
    const long long n0 = BC * 1024 * 1024;
    const long long n1 = BC * 512 * 512;
    const long long n2 = BC * 256 * 256;

    float* out0 = out;            // lap0
    float* out1 = out0 + n0;      // lap1
    float* out2 = out1 + n1;      // lap2
    float* out3 = out2 + n2;      // down2

    float* ws0 = (float*)d_ws;    // down0
    float* ws1 = ws0 + n1;        // down1

    lap_level_kernel<<<dim3(1024 / TW, 1024 / TH, (int)BC), 256, 0, stream>>>(
        img, out0, ws0, 1024, 1024);
    lap_level_kernel<<<dim3(512 / TW, 512 / TH, (int)BC), 256, 0, stream>>>(
        ws0, out1, ws1, 512, 512);
    lap_level_kernel<<<dim3(256 / TW, 256 / TH, (int)BC), 256, 0, stream>>>(
        ws1, out2, out3, 256, 256);
}

// Round 12
// 92.881 us; speedup vs baseline: 2.1867x; 1.2004x over previous
//
#include <hip/hip_runtime.h>

#define TILE 64          // 64x64 lap tile per block
#define DR 34            // tmp/down rows incl. 1-ring halo (TILE/2 + 2)
#define NCH 18           // float4 chunks per tmp row (72 cols = TILE + 8)
#define TMPP 76          // s_tmp row stride (16B-multiple)
#define SDP 35           // s_down row stride (odd -> bank spread)
#define NBV (DR * NCH)   // 612 vertical tasks
#define NBH (DR * 17)    // 578 horizontal tasks

__device__ __forceinline__ int refl(int t, int n) {
    if (t < 0) t = -t;
    if (t >= n) t = 2 * (n - 1) - t;
    return t;
}

// One fused pyramid level: down = gauss5(cur)[::2,::2]; lap = cur - up(down).
// R6's proven 3-phase/2-barrier structure, 64x64 tile, with a dual-task Bv
// burst: 10 independent float4 loads in flight per thread (Little's-law fix
// for the measured 3.1 TB/s plateau at 5-deep). launch_bounds(256,6) keeps
// 85-VGPR headroom so the burst cannot spill (R9/R10 lesson: spill shows as
// symmetric FETCH+WRITE inflation). Halo down values follow the chain
// convention (reflect inherited from reflected reads + kernel symmetry),
// exactly what the up-stencil needs (validated R3-R6).
__global__ __launch_bounds__(256, 6) void lap_level_kernel(
    const float* __restrict__ cur, float* __restrict__ lap,
    float* __restrict__ down, int H, int W)
{
    __shared__ float s_tmp[DR][TMPP];
    __shared__ float s_down[DR][SDP];

    const int x0 = blockIdx.x * TILE, y0 = blockIdx.y * TILE;
    const int img = blockIdx.z;
    const int Hh = H >> 1, Wh = W >> 1;
    const int tid = threadIdx.x;

    const float* curb = cur + (size_t)img * H * W;

    // ---- Bv: vertical 5-tap -> s_tmp[a][c] (tmp row a = down row y0/2-1+a,
    //      center pixel row y0+2a-2; cols x0-4 .. x0+67) ----
    const bool border = (x0 == 0) | (y0 == 0) | (x0 + TILE == W) | (y0 + TILE == H);
    if (!border) {
        for (int k = tid; k < NBV; k += 512) {
            // task A
            int a0 = k / NCH, c0 = (k - a0 * NCH) * 4;
            const float* p0 = curb + (size_t)(y0 - 4 + 2 * a0) * W + (x0 - 4 + c0);
            float4 A0 = *(const float4*)(p0);
            float4 A1 = *(const float4*)(p0 + (size_t)W);
            float4 A2 = *(const float4*)(p0 + (size_t)2 * W);
            float4 A3 = *(const float4*)(p0 + (size_t)3 * W);
            float4 A4 = *(const float4*)(p0 + (size_t)4 * W);
            // task B (k+256 < 612 always on trip 1; absent on trip 2)
            const int k1 = k + 256;
            const bool h1 = k1 < NBV;
            int a1 = 0, c1 = 0;
            float4 B0, B1, B2, B3, B4;
            if (h1) {
                a1 = k1 / NCH; c1 = (k1 - a1 * NCH) * 4;
                const float* p1 = curb + (size_t)(y0 - 4 + 2 * a1) * W + (x0 - 4 + c1);
                B0 = *(const float4*)(p1);
                B1 = *(const float4*)(p1 + (size_t)W);
                B2 = *(const float4*)(p1 + (size_t)2 * W);
                B3 = *(const float4*)(p1 + (size_t)3 * W);
                B4 = *(const float4*)(p1 + (size_t)4 * W);
            }
            float4 t0;
            t0.x = A0.x + 4.f * A1.x + 6.f * A2.x + 4.f * A3.x + A4.x;
            t0.y = A0.y + 4.f * A1.y + 6.f * A2.y + 4.f * A3.y + A4.y;
            t0.z = A0.z + 4.f * A1.z + 6.f * A2.z + 4.f * A3.z + A4.z;
            t0.w = A0.w + 4.f * A1.w + 6.f * A2.w + 4.f * A3.w + A4.w;
            *(float4*)&s_tmp[a0][c0] = t0;
            if (h1) {
                float4 t1;
                t1.x = B0.x + 4.f * B1.x + 6.f * B2.x + 4.f * B3.x + B4.x;
                t1.y = B0.y + 4.f * B1.y + 6.f * B2.y + 4.f * B3.y + B4.y;
                t1.z = B0.z + 4.f * B1.z + 6.f * B2.z + 4.f * B3.z + B4.z;
                t1.w = B0.w + 4.f * B1.w + 6.f * B2.w + 4.f * B3.w + B4.w;
                *(float4*)&s_tmp[a1][c1] = t1;
            }
        }
    } else {
        for (int k = tid; k < DR * 72; k += 256) {
            int a = k / 72, c = k - a * 72;
            int gx = refl(x0 - 4 + c, W);
            int r0 = y0 - 4 + 2 * a;
            const float wv[5] = {1.f, 4.f, 6.f, 4.f, 1.f};
            float acc = 0.f;
#pragma unroll
            for (int u = 0; u < 5; ++u)
                acc += wv[u] * curb[(size_t)refl(r0 + u, H) * W + gx];
            s_tmp[a][c] = acc;
        }
    }
    __syncthreads();

    // ---- Bh: horizontal 5-tap; 2 down values per task; interior -> HBM ----
    float* downb = down + (size_t)img * Hh * Wh;
    for (int k = tid; k < NBH; k += 256) {
        int a = k / 17, b2 = k - a * 17;
        float4 A = *(const float4*)&s_tmp[a][4 * b2];
        float4 B = *(const float4*)&s_tmp[a][4 * b2 + 4];
        float v0 = (A.x + 4.f * A.y + 6.f * A.z + 4.f * A.w + B.x) * (1.f / 256.f);
        float v1 = (A.z + 4.f * A.w + 6.f * B.x + 4.f * B.y + B.z) * (1.f / 256.f);
        s_down[a][2 * b2] = v0;
        s_down[a][2 * b2 + 1] = v1;
        if ((unsigned)(a - 1) < 32u) {
            size_t rowoff = (size_t)((y0 >> 1) - 1 + a) * Wh + ((x0 >> 1) - 1);
            if (b2 >= 1) downb[rowoff + 2 * b2] = v0;
            if (b2 <= 15) downb[rowoff + 2 * b2 + 1] = v1;
        }
    }
    __syncthreads();

    // ---- C: lap = cur - up(down); 4x4 px/thread (R3's proven layout);
    //      cur re-read from global (L2-hot from Bv) ----
    const int tx = tid & 15, ty = tid >> 4;
    float d[4][4];
#pragma unroll
    for (int r = 0; r < 4; ++r)
#pragma unroll
        for (int c = 0; c < 4; ++c)
            d[r][c] = s_down[2 * ty + r][2 * tx + c];
    float ve[2][4], vo[2][4];
#pragma unroll
    for (int r2 = 0; r2 < 2; ++r2)
#pragma unroll
        for (int c = 0; c < 4; ++c) {
            ve[r2][c] = d[r2][c] + 6.f * d[r2 + 1][c] + d[r2 + 2][c];
            vo[r2][c] = 4.f * (d[r2 + 1][c] + d[r2 + 2][c]);
        }
    float* lapb = lap + (size_t)img * H * W;
    const int ib = y0 + 4 * ty, jb = x0 + 4 * tx;
#pragma unroll
    for (int rr = 0; rr < 4; ++rr) {
        const int r2 = rr >> 1;
        float4 cv = *(const float4*)(curb + (size_t)(ib + rr) * W + jb);
        float u0, u1, u2, u3;
        if ((rr & 1) == 0) {
            u0 = ve[r2][0] + 6.f * ve[r2][1] + ve[r2][2];
            u1 = 4.f * (ve[r2][1] + ve[r2][2]);
            u2 = ve[r2][1] + 6.f * ve[r2][2] + ve[r2][3];
            u3 = 4.f * (ve[r2][2] + ve[r2][3]);
        } else {
            u0 = vo[r2][0] + 6.f * vo[r2][1] + vo[r2][2];
            u1 = 4.f * (vo[r2][1] + vo[r2][2]);
            u2 = vo[r2][1] + 6.f * vo[r2][2] + vo[r2][3];
            u3 = 4.f * (vo[r2][2] + vo[r2][3]);
        }
        float4 o;
        o.x = cv.x - u0 * (1.f / 64.f);
        o.y = cv.y - u1 * (1.f / 64.f);
        o.z = cv.z - u2 * (1.f / 64.f);
        o.w = cv.w - u3 * (1.f / 64.f);
        *(float4*)(lapb + (size_t)(ib + rr) * W + jb) = o;
    }
}

extern "C" void kernel_launch(void* const* d_in, const int* in_sizes, int n_in,
                              void* d_out, int out_size, void* d_ws, size_t ws_size,
                              hipStream_t stream) {
    const float* img = (const float*)d_in[0];
    float* out = (float*)d_out;

    const long long BC = 8LL * 3;
    const long long n0 = BC * 1024 * 1024;
    const long long n1 = BC * 512 * 512;
    const long long n2 = BC * 256 * 256;

    float* out0 = out;            // lap0
    float* out1 = out0 + n0;      // lap1
    float* out2 = out1 + n1;      // lap2
    float* out3 = out2 + n2;      // down2

    float* ws0 = (float*)d_ws;    // down0
    float* ws1 = ws0 + n1;        // down1

    lap_level_kernel<<<dim3(1024 / TILE, 1024 / TILE, (int)BC), 256, 0, stream>>>(
        img, out0, ws0, 1024, 1024);
    lap_level_kernel<<<dim3(512 / TILE, 512 / TILE, (int)BC), 256, 0, stream>>>(
        ws0, out1, ws1, 512, 512);
    lap_level_kernel<<<dim3(256 / TILE, 256 / TILE, (int)BC), 256, 0, stream>>>(
        ws1, out2, out3, 256, 256);
}

// Round 13
// 71.800 us; speedup vs baseline: 2.8288x; 1.2936x over previous
//
#include <hip/hip_runtime.h>

// Barrier-free, LDS-free scanline Laplacian-pyramid level.
// Wave = 128-px-wide strip x sh rows. Rolling 5-row register window;
// ALL cross-lane exchange via __shfl (in-order VALU) -- no LDS, no barriers,
// so the R11 masked-LDS-write hazard class is gone entirely.
// Lane l owns pixel cols x0+2l, x0+2l+1. Halo cols live in lanes 0,1,62,63's
// second rolling window and are routed by broadcast shuffles.
// Loads for row-pair a+1 issue before iteration a's math -> loads outstanding
// continuously (Little's-law fix for the measured 3.3 TB/s phase-burst bound).

__device__ __forceinline__ int refl(int t, int n) {
    if (t < 0) t = -t;
    if (t >= n) t = 2 * (n - 1) - t;
    return t;
}

__global__ __launch_bounds__(256, 6) void lap_scan_kernel(
    const float* __restrict__ cur, float* __restrict__ lap,
    float* __restrict__ down, int H, int W, int sh)
{
    const int wid = threadIdx.x >> 6, lane = threadIdx.x & 63;
    const int x0 = blockIdx.x * 128;
    const int y0 = (blockIdx.y * 4 + wid) * sh;
    const int img = blockIdx.z;
    const int Hh = H >> 1, Wh = W >> 1;

    const float* curb = cur + (size_t)img * H * W;
    float* lapb = lap + (size_t)img * H * W;
    float* downb = down + (size_t)img * Hh * Wh;

    const int c0 = x0 + 2 * lane;                       // own col pair (in-image)
    const bool haloLane = (lane < 2) | (lane >= 62);
    // halo pairs: lane0:(x0-4,-3) lane1:(x0-2,-1) lane62:(x0+128,129) lane63:(x0+130,131)
    const int hc0 = (lane < 2) ? (x0 - 4 + 2 * lane) : (x0 + 4 + 2 * lane);
    const bool xb = (x0 == 0) || (x0 + 128 == W);
    const int hg0 = refl(hc0, W), hg1 = refl(hc0 + 1, W);

    auto loadOwn = [&](int rho) -> float2 {
        return *(const float2*)(curb + (size_t)refl(y0 + rho, H) * W + c0);
    };
    auto loadHalo = [&](int rho) -> float2 {
        const float* rp = curb + (size_t)refl(y0 + rho, H) * W;
        float2 v;
        if (xb) { v.x = rp[hg0]; v.y = rp[hg1]; }
        else    { v = *(const float2*)(rp + hc0); }
        return v;
    };

    // prologue: window = pixel rows y0-4 .. y0 (iteration a covers 2a-2..2a+2)
    float2 w0 = loadOwn(-4), w1 = loadOwn(-3), w2 = loadOwn(-2),
           w3 = loadOwn(-1), w4 = loadOwn(0);
    float2 h0 = {0,0}, h1 = {0,0}, h2 = {0,0}, h3 = {0,0}, h4 = {0,0};
    if (haloLane) {
        h0 = loadHalo(-4); h1 = loadHalo(-3); h2 = loadHalo(-2);
        h3 = loadHalo(-1); h4 = loadHalo(0);
    }

    float dm2a = 0, dm2b = 0, dm2c = 0, dm1a = 0, dm1b = 0, dm1c = 0;
    const int aEnd = sh >> 1;

    for (int a = -1; a <= aEnd; ++a) {
        // 1. issue next row-pair loads; they land under this iteration's math
        float2 nw3 = {0,0}, nw4 = {0,0}, nh3 = {0,0}, nh4 = {0,0};
        const bool more = (a < aEnd);
        if (more) {
            nw3 = loadOwn(2 * a + 3); nw4 = loadOwn(2 * a + 4);
            if (haloLane) { nh3 = loadHalo(2 * a + 3); nh4 = loadHalo(2 * a + 4); }
        }

        // 2. vertical 5-tap (own + halo cols)
        float vE = w0.x + 4.f * w1.x + 6.f * w2.x + 4.f * w3.x + w4.x;
        float vO = w0.y + 4.f * w1.y + 6.f * w2.y + 4.f * w3.y + w4.y;
        float hE = h0.x + 4.f * h1.x + 6.f * h2.x + 4.f * h3.x + h4.x;
        float hO = h0.y + 4.f * h1.y + 6.f * h2.y + 4.f * h3.y + h4.y;

        // 3. route halo/edge values (all-lane uniform broadcasts)
        float bhE0 = __shfl(hE, 0),  bhO0 = __shfl(hO, 0);
        float bhE1 = __shfl(hE, 1),  bhO1 = __shfl(hO, 1);
        float bhE62 = __shfl(hE, 62), bhO62 = __shfl(hO, 62);
        float bhE63 = __shfl(hE, 63);
        float bvE0 = __shfl(vE, 0);
        float bvE63 = __shfl(vE, 63), bvO63 = __shfl(vO, 63);

        float sE = __shfl_up(vE, 1), sO = __shfl_up(vO, 1);
        float nE = __shfl_down(vE, 1);
        float eL = (lane == 0) ? bhE1 : sE;    // t(c0-2)
        float oL = (lane == 0) ? bhO1 : sO;    // t(c0-1)
        float eR = (lane == 63) ? bhE62 : nE;  // t(c0+2)

        // 4. horizontal 5-tap -> down value at down col x0/2+lane (row y0/2+a)
        float dv = (eL + 4.f * oL + 6.f * vE + 4.f * vO + eR) * (1.f / 256.f);
        // halo down cols x0/2-1 and x0/2+64 (same value on every lane)
        float dvm1 = (bhE0 + 4.f * bhO0 + 6.f * bhE1 + 4.f * bhO1 + bvE0) * (1.f / 256.f);
        float dvp64 = (bvE63 + 4.f * bvO63 + 6.f * bhE62 + 4.f * bhO62 + bhE63) * (1.f / 256.f);

        // 5. neighbor triplet (down cols lane-1, lane, lane+1)
        float su = __shfl_up(dv, 1), sd = __shfl_down(dv, 1);
        float da = (lane == 0) ? dvm1 : su;
        float db = dv;
        float dc = (lane == 63) ? dvp64 : sd;

        if (a >= 0 && a < aEnd)
            downb[(size_t)((y0 >> 1) + a) * Wh + (x0 >> 1) + lane] = dv;

        // 6. emit lap rows y0+2a-2 (=w0) and y0+2a-1 (=w1)
        if (a >= 1) {
            float CEa = dm2a + 6.f * dm1a + da;
            float CEb = dm2b + 6.f * dm1b + db;
            float CEc = dm2c + 6.f * dm1c + dc;
            float COa = 4.f * (dm1a + da);
            float COb = 4.f * (dm1b + db);
            float COc = 4.f * (dm1c + dc);
            float2 oe, oo;
            oe.x = w0.x - (CEa + 6.f * CEb + CEc) * (1.f / 64.f);
            oe.y = w0.y - 4.f * (CEb + CEc) * (1.f / 64.f);
            oo.x = w1.x - (COa + 6.f * COb + COc) * (1.f / 64.f);
            oo.y = w1.y - 4.f * (COb + COc) * (1.f / 64.f);
            *(float2*)(lapb + (size_t)(y0 + 2 * a - 2) * W + c0) = oe;
            *(float2*)(lapb + (size_t)(y0 + 2 * a - 1) * W + c0) = oo;
        }

        // 7. shift rolling state
        dm2a = dm1a; dm2b = dm1b; dm2c = dm1c;
        dm1a = da;   dm1b = db;   dm1c = dc;
        w0 = w2; w1 = w3; w2 = w4;
        if (more) { w3 = nw3; w4 = nw4; }
        h0 = h2; h1 = h3; h2 = h4;
        if (more) { h3 = nh3; h4 = nh4; }
    }
}

extern "C" void kernel_launch(void* const* d_in, const int* in_sizes, int n_in,
                              void* d_out, int out_size, void* d_ws, size_t ws_size,
                              hipStream_t stream) {
    const float* img = (const float*)d_in[0];
    float* out = (float*)d_out;

    const long long BC = 8LL * 3;
    const long long n0 = BC * 1024 * 1024;
    const long long n1 = BC * 512 * 512;
    const long long n2 = BC * 256 * 256;

    float* out0 = out;            // lap0
    float* out1 = out0 + n0;      // lap1
    float* out2 = out1 + n1;      // lap2
    float* out3 = out2 + n2;      // down2

    float* ws0 = (float*)d_ws;    // down0
    float* ws1 = ws0 + n1;        // down1

    // grid: (W/128 strips, H/(4*sh) wave-quads, 24 images)
    lap_scan_kernel<<<dim3(1024 / 128, 1024 / (4 * 32), (int)BC), 256, 0, stream>>>(
        img, out0, ws0, 1024, 1024, 32);
    lap_scan_kernel<<<dim3(512 / 128, 512 / (4 * 16), (int)BC), 256, 0, stream>>>(
        ws0, out1, ws1, 512, 512, 16);
    lap_scan_kernel<<<dim3(256 / 128, 256 / (4 * 8), (int)BC), 256, 0, stream>>>(
        ws1, out2, out3, 256, 256, 8);
}